// Round 1
// baseline (404.755 us; speedup 1.0000x reference)
//
#include <hip/hip_runtime.h>

#define NB 8192
#define ACC_OFF (3 * 2 * NB)   // word offset of per-layer n^2 accumulators in ws

// Fused kernel: per-position channel norms + d histogram (counts+sums) + n^2 sum.
// Grid: 4096 blocks (layer0) + 1024 (layer1) + 256 (layer2) = 5376, 256 threads.
// Block = 64 consecutive (h,w) positions x all C channels of one batch image.
// Thread (cg, p): channel group cg (C/4 channels), position p. Loads coalesced
// 64 consecutive floats per wave per channel.
__global__ __launch_bounds__(256) void stfpm_hist(
    const float* __restrict__ t0, const float* __restrict__ s0, const float* __restrict__ n0,
    const float* __restrict__ t1, const float* __restrict__ s1, const float* __restrict__ n1,
    const float* __restrict__ t2, const float* __restrict__ s2, const float* __restrict__ n2,
    unsigned int* __restrict__ ws_u, float* __restrict__ ws_f)
{
    __shared__ unsigned int cnt_sh[NB];   // 32 KB
    __shared__ float        sum_sh[NB];   // 32 KB  (total 64 KB -> 2 blocks/CU)

    const int bid = blockIdx.x;
    int layer, lb, C, hwShift;
    const float *t, *s, *n;
    if (bid < 4096)      { layer = 0; lb = bid;        C = 64;  hwShift = 14; t = t0; s = s0; n = n0; }
    else if (bid < 5120) { layer = 1; lb = bid - 4096; C = 128; hwShift = 12; t = t1; s = s1; n = n1; }
    else                 { layer = 2; lb = bid - 5120; C = 256; hwShift = 10; t = t2; s = s2; n = n2; }

    const int HW  = 1 << hwShift;
    const int tid = threadIdx.x;
    const int p   = tid & 63;     // position within block's 64
    const int cg  = tid >> 6;     // channel group (= wave id)
    const int Cg  = C >> 2;       // channels per group: 16 / 32 / 64

    const int p0 = lb << 6;              // first flat position of this block
    const int b  = p0 >> hwShift;        // batch index (blocks never straddle b)
    const int q  = p0 & (HW - 1);        // (h,w) flat offset, contiguous in memory
    const int c0 = cg * Cg;
    const size_t off0 = (size_t)(b * C + c0) * HW + q + p;

    const float* tp  = t + off0;
    const float* sp  = s + off0;
    const float* np_ = n + off0;

    // ---- pass 1: sum of squares over this thread's channels ----
    float aT = 0.f, aS = 0.f, aN = 0.f;
    #pragma unroll 4
    for (int i = 0; i < Cg; ++i) {
        size_t o = (size_t)i * HW;
        float x = tp[o], y = sp[o], z = np_[o];
        aT += x * x; aS += y * y; aN += z * z;
    }
    // wave-reduce n^2 partial (64 lanes)
    for (int o = 32; o > 0; o >>= 1) aN += __shfl_down(aN, o, 64);

    // cross-wave combine of per-position partials via LDS overlay on cnt_sh
    float* ov = (float*)cnt_sh;
    ov[cg * 64 + p]       = aT;     // [0,256)
    ov[256 + cg * 64 + p] = aS;     // [256,512)
    if (p == 0) ov[512 + cg] = aN;  // [512,516)
    __syncthreads();

    float nT = ov[p] + ov[64 + p] + ov[128 + p] + ov[192 + p];
    float nS = ov[256 + p] + ov[320 + p] + ov[384 + p] + ov[448 + p];
    float invT = 1.f / fmaxf(sqrtf(nT), 1e-12f);
    float invS = 1.f / fmaxf(sqrtf(nS), 1e-12f);
    if (tid == 0) {
        float nn = ov[512] + ov[513] + ov[514] + ov[515];
        atomicAdd(&ws_f[ACC_OFF + layer], nn);
    }
    __syncthreads();

    // ---- zero histogram ----
    for (int i = tid; i < NB; i += 256) { cnt_sh[i] = 0u; sum_sh[i] = 0.f; }
    __syncthreads();

    // ---- pass 2: d = (t*invT - s*invS)^2, histogram on float bit pattern ----
    // (re-reads hit L1/L2: block working set is 32-128 KB)
    #pragma unroll 4
    for (int i = 0; i < Cg; ++i) {
        size_t o = (size_t)i * HW;
        float a = tp[o] * invT - sp[o] * invS;
        float d = a * a;
        unsigned bin = __float_as_uint(d) >> 19;  // d in [0,4] -> bin <= 2064
        atomicAdd(&cnt_sh[bin], 1u);
        atomicAdd(&sum_sh[bin], d);
    }
    __syncthreads();

    // ---- flush nonzero bins to global per-layer histogram ----
    unsigned int* gc = ws_u + layer * 2 * NB;
    float*        gs = ws_f + layer * 2 * NB + NB;
    for (int i = tid; i < NB; i += 256) {
        unsigned c = cnt_sh[i];
        if (c) { atomicAdd(&gc[i], c); atomicAdd(&gs[i], sum_sh[i]); }
    }
}

// Single block: per layer, scan bins from the top to find the boundary bin for
// the exact top-cnt count; full bins above are summed exactly, boundary bin uses
// a uniform-within-bin model. Adds mean(n^2), writes scalar total.
__global__ __launch_bounds__(256) void stfpm_finalize(
    const unsigned int* __restrict__ ws_u, const float* __restrict__ ws_f,
    float* __restrict__ out)
{
    __shared__ unsigned int cchunk[256];
    __shared__ float        schunk[256];
    const int tid = threadIdx.x;

    // cnt = N - 1 - floor(0.999*(N-1)) per layer
    const int   targets[3] = {16778, 8389, 4195};
    const float Ns[3]      = {16777216.f, 8388608.f, 4194304.f};
    const int   CHUNK = NB / 256;  // 32

    float total = 0.f;  // thread 0 only
    for (int layer = 0; layer < 3; ++layer) {
        const unsigned int* gc = ws_u + layer * 2 * NB;
        const float*        gs = ws_f + layer * 2 * NB + NB;
        unsigned int c = 0; float sv = 0.f;
        const int b0 = tid * CHUNK;
        for (int i = 0; i < CHUNK; ++i) { c += gc[b0 + i]; sv += gs[b0 + i]; }
        __syncthreads();  // previous iteration's reads done before overwrite
        cchunk[tid] = c; schunk[tid] = sv;
        __syncthreads();
        if (tid == 0) {
            const int target = targets[layer];
            long long cum = 0; float sAbove = 0.f;
            int ch = 255;
            while (ch >= 0 && cum + (long long)cchunk[ch] < target) {
                cum += cchunk[ch]; sAbove += schunk[ch]; --ch;
            }
            int bin = ch * CHUNK + CHUNK - 1;
            while (bin >= ch * CHUNK && cum + (long long)gc[bin] < target) {
                cum += gc[bin]; sAbove += gs[bin]; --bin;
            }
            unsigned cb = gc[bin];          // boundary bin count (>=1)
            float    sb = gs[bin];
            int j = target - (int)cum;      // elements taken from boundary bin
            float lo = __uint_as_float((unsigned)bin << 19);
            float hi = __uint_as_float((unsigned)(bin + 1) << 19);
            float w  = hi - lo;
            float m  = sb / (float)cb;                 // actual bin mean
            float f  = (float)j / (float)cb;
            float topmean = m + w * (1.0f - f) * 0.5f; // mean of top-j under uniform model
            topmean = fminf(fmaxf(topmean, lo), hi);
            float hard   = (sAbove + topmean * (float)j) / (float)target;
            float n2mean = ws_f[ACC_OFF + layer] / Ns[layer];
            total += hard + n2mean;
        }
        __syncthreads();
    }
    if (tid == 0) out[0] = total;
}

extern "C" void kernel_launch(void* const* d_in, const int* in_sizes, int n_in,
                              void* d_out, int out_size, void* d_ws, size_t ws_size,
                              hipStream_t stream)
{
    const float* t0 = (const float*)d_in[0];
    const float* s0 = (const float*)d_in[1];
    const float* n0 = (const float*)d_in[2];
    const float* t1 = (const float*)d_in[3];
    const float* s1 = (const float*)d_in[4];
    const float* n1 = (const float*)d_in[5];
    const float* t2 = (const float*)d_in[6];
    const float* s2 = (const float*)d_in[7];
    const float* n2 = (const float*)d_in[8];

    // zero per-layer histograms + accumulators (ws is NOT re-poisoned between replays)
    hipMemsetAsync(d_ws, 0, (size_t)(ACC_OFF + 8) * 4, stream);

    stfpm_hist<<<5376, 256, 0, stream>>>(t0, s0, n0, t1, s1, n1, t2, s2, n2,
                                         (unsigned int*)d_ws, (float*)d_ws);
    stfpm_finalize<<<1, 256, 0, stream>>>((const unsigned int*)d_ws,
                                          (const float*)d_ws, (float*)d_out);
}

// Round 2
// 241.826 us; speedup vs baseline: 1.6737x; 1.6737x over previous
//
#include <hip/hip_runtime.h>

#define NBINS 2304                    // d = (t_hat - s_hat)^2 <= 4 -> bin <= 2064
#define ACC_OFF (3 * 2 * NBINS)       // word offset of per-layer n^2 accumulators in ws

// Fused kernel: per-position channel norms + d histogram (counts+sums) + n^2 sum.
// Grid: 256 blocks (layer2, heaviest, dispatched first) + 1024 (layer1) + 4096 (layer0).
// Block = 64 consecutive (h,w) positions x all C channels of one batch image.
// Thread (cg, p): channel group cg (C/4 channels), position p. Loads coalesced
// 64 consecutive floats per wave per channel.
__global__ __launch_bounds__(256, 6) void stfpm_hist(
    const float* __restrict__ t0, const float* __restrict__ s0, const float* __restrict__ n0,
    const float* __restrict__ t1, const float* __restrict__ s1, const float* __restrict__ n1,
    const float* __restrict__ t2, const float* __restrict__ s2, const float* __restrict__ n2,
    unsigned int* __restrict__ ws_u, float* __restrict__ ws_f)
{
    __shared__ unsigned int cnt_sh[NBINS];   // 9 KB
    __shared__ float        sum_sh[NBINS];   // 9 KB  (18 KB total -> LDS no longer caps occupancy)

    const int bid = blockIdx.x;
    int layer, lb, C, hwShift;
    const float *t, *s, *n;
    if (bid < 256)       { layer = 2; lb = bid;        C = 256; hwShift = 10; t = t2; s = s2; n = n2; }
    else if (bid < 1280) { layer = 1; lb = bid - 256;  C = 128; hwShift = 12; t = t1; s = s1; n = n1; }
    else                 { layer = 0; lb = bid - 1280; C = 64;  hwShift = 14; t = t0; s = s0; n = n0; }

    const int HW  = 1 << hwShift;
    const int tid = threadIdx.x;
    const int p   = tid & 63;     // position within block's 64
    const int cg  = tid >> 6;     // channel group (= wave id)
    const int Cg  = C >> 2;       // channels per group: 16 / 32 / 64

    const int p0 = lb << 6;              // first flat position of this block
    const int b  = p0 >> hwShift;        // batch index (blocks never straddle b)
    const int q  = p0 & (HW - 1);        // (h,w) flat offset, contiguous in memory
    const int c0 = cg * Cg;
    const size_t off0 = (size_t)(b * C + c0) * HW + q + p;

    const float* tp  = t + off0;
    const float* sp  = s + off0;
    const float* np_ = n + off0;

    // ---- pass 1: sum of squares over this thread's channels ----
    float aT = 0.f, aS = 0.f, aN = 0.f;
    #pragma unroll 4
    for (int i = 0; i < Cg; ++i) {
        size_t o = (size_t)i * HW;
        float x = tp[o], y = sp[o], z = np_[o];
        aT += x * x; aS += y * y; aN += z * z;
    }
    // wave-reduce n^2 partial (64 lanes)
    for (int o = 32; o > 0; o >>= 1) aN += __shfl_down(aN, o, 64);

    // cross-wave combine of per-position partials via LDS overlay on cnt_sh
    float* ov = (float*)cnt_sh;
    ov[cg * 64 + p]       = aT;     // [0,256)
    ov[256 + cg * 64 + p] = aS;     // [256,512)
    if (p == 0) ov[512 + cg] = aN;  // [512,516)
    __syncthreads();

    float nT = ov[p] + ov[64 + p] + ov[128 + p] + ov[192 + p];
    float nS = ov[256 + p] + ov[320 + p] + ov[384 + p] + ov[448 + p];
    float invT = 1.f / fmaxf(sqrtf(nT), 1e-12f);
    float invS = 1.f / fmaxf(sqrtf(nS), 1e-12f);
    if (tid == 0) {
        float nn = ov[512] + ov[513] + ov[514] + ov[515];
        atomicAdd(&ws_f[ACC_OFF + layer], nn);
    }
    __syncthreads();

    // ---- zero histogram ----
    for (int i = tid; i < NBINS; i += 256) { cnt_sh[i] = 0u; sum_sh[i] = 0.f; }
    __syncthreads();

    // ---- pass 2: d = (t*invT - s*invS)^2, histogram on float bit pattern ----
    // (re-reads hit L1/L2: block working set is 32-128 KB)
    #pragma unroll 4
    for (int i = 0; i < Cg; ++i) {
        size_t o = (size_t)i * HW;
        float a = tp[o] * invT - sp[o] * invS;
        float d = a * a;
        unsigned bin = __float_as_uint(d) >> 19;  // d in [0,4] -> bin <= 2064
        bin = min(bin, (unsigned)(NBINS - 1));
        atomicAdd(&cnt_sh[bin], 1u);
        atomicAdd(&sum_sh[bin], d);
    }
    __syncthreads();

    // ---- flush nonzero bins to global per-layer histogram ----
    unsigned int* gc = ws_u + layer * 2 * NBINS;
    float*        gs = ws_f + layer * 2 * NBINS + NBINS;
    for (int i = tid; i < NBINS; i += 256) {
        unsigned c = cnt_sh[i];
        if (c) { atomicAdd(&gc[i], c); atomicAdd(&gs[i], sum_sh[i]); }
    }
}

// Single block: per layer, scan bins from the top to find the boundary bin for
// the exact top-cnt count; full bins above are summed exactly, boundary bin uses
// a uniform-within-bin model. Adds mean(n^2), writes scalar total.
__global__ __launch_bounds__(256) void stfpm_finalize(
    const unsigned int* __restrict__ ws_u, const float* __restrict__ ws_f,
    float* __restrict__ out)
{
    __shared__ unsigned int cchunk[256];
    __shared__ float        schunk[256];
    const int tid = threadIdx.x;

    // cnt = N - 1 - floor(0.999*(N-1)) per layer
    const int   targets[3] = {16778, 8389, 4195};
    const float Ns[3]      = {16777216.f, 8388608.f, 4194304.f};
    const int   CHUNK = NBINS / 256;  // 9

    float total = 0.f;  // thread 0 only
    for (int layer = 0; layer < 3; ++layer) {
        const unsigned int* gc = ws_u + layer * 2 * NBINS;
        const float*        gs = ws_f + layer * 2 * NBINS + NBINS;
        unsigned int c = 0; float sv = 0.f;
        const int b0 = tid * CHUNK;
        for (int i = 0; i < CHUNK; ++i) { c += gc[b0 + i]; sv += gs[b0 + i]; }
        __syncthreads();  // previous iteration's reads done before overwrite
        cchunk[tid] = c; schunk[tid] = sv;
        __syncthreads();
        if (tid == 0) {
            const int target = targets[layer];
            long long cum = 0; float sAbove = 0.f;
            int ch = 255;
            while (ch >= 0 && cum + (long long)cchunk[ch] < target) {
                cum += cchunk[ch]; sAbove += schunk[ch]; --ch;
            }
            int bin = ch * CHUNK + CHUNK - 1;
            while (bin >= ch * CHUNK && cum + (long long)gc[bin] < target) {
                cum += gc[bin]; sAbove += gs[bin]; --bin;
            }
            unsigned cb = gc[bin];          // boundary bin count (>=1)
            float    sb = gs[bin];
            int j = target - (int)cum;      // elements taken from boundary bin
            float lo = __uint_as_float((unsigned)bin << 19);
            float hi = __uint_as_float((unsigned)(bin + 1) << 19);
            float w  = hi - lo;
            float m  = sb / (float)cb;                 // actual bin mean
            float f  = (float)j / (float)cb;
            float topmean = m + w * (1.0f - f) * 0.5f; // mean of top-j under uniform model
            topmean = fminf(fmaxf(topmean, lo), hi);
            float hard   = (sAbove + topmean * (float)j) / (float)target;
            float n2mean = ws_f[ACC_OFF + layer] / Ns[layer];
            total += hard + n2mean;
        }
        __syncthreads();
    }
    if (tid == 0) out[0] = total;
}

extern "C" void kernel_launch(void* const* d_in, const int* in_sizes, int n_in,
                              void* d_out, int out_size, void* d_ws, size_t ws_size,
                              hipStream_t stream)
{
    const float* t0 = (const float*)d_in[0];
    const float* s0 = (const float*)d_in[1];
    const float* n0 = (const float*)d_in[2];
    const float* t1 = (const float*)d_in[3];
    const float* s1 = (const float*)d_in[4];
    const float* n1 = (const float*)d_in[5];
    const float* t2 = (const float*)d_in[6];
    const float* s2 = (const float*)d_in[7];
    const float* n2 = (const float*)d_in[8];

    // zero per-layer histograms + accumulators (ws is NOT re-poisoned between replays)
    hipMemsetAsync(d_ws, 0, (size_t)(ACC_OFF + 8) * 4, stream);

    stfpm_hist<<<5376, 256, 0, stream>>>(t0, s0, n0, t1, s1, n1, t2, s2, n2,
                                         (unsigned int*)d_ws, (float*)d_ws);
    stfpm_finalize<<<1, 256, 0, stream>>>((const unsigned int*)d_ws,
                                          (const float*)d_ws, (float*)d_out);
}

// Round 3
// 118.837 us; speedup vs baseline: 3.4060x; 2.0349x over previous
//
#include <hip/hip_runtime.h>

#define NBINS 4352                 // bin = float_bits(d)>>18 ; d<=4 -> bin<=4128
#define ACC_OFF (3 * NBINS)        // word offset of per-layer n^2 accumulators in ws

typedef float f4v __attribute__((ext_vector_type(4)));

// Per-layer fused body. Block = 256 consecutive (h,w) positions x all C channels
// of one batch image. Wave w owns channel chunk [w*C/4, (w+1)*C/4); lane l owns
// positions 4l..4l+3 (float4 loads, 1KB per wave-load).
template<int C, int HWSHIFT, int LAYER>
__device__ __forceinline__ void hist_layer(
    const float* __restrict__ t, const float* __restrict__ s, const float* __restrict__ n,
    int lb, unsigned int* __restrict__ ws_u, float* __restrict__ ws_f,
    unsigned int* cnt_sh, float* inv_sh)
{
    const int HW  = 1 << HWSHIFT;
    const int Cg  = C >> 2;            // channels per wave
    const int tid = threadIdx.x;
    const int w   = tid >> 6;
    const int l   = tid & 63;

    const int p0 = lb << 8;            // first of this block's 256 positions
    const int b  = p0 >> HWSHIFT;      // batch image (blocks never straddle)
    const int q  = p0 & (HW - 1);
    const size_t base = ((size_t)(b * C + w * Cg)) * HW + q + 4 * l;

    const float* tp = t + base;
    const float* sp = s + base;
    const float* np = n + base;

    // ---- pass 1: per-position sum of squares + n^2 ----
    float aT0=0,aT1=0,aT2=0,aT3=0, aS0=0,aS1=0,aS2=0,aS3=0, aN=0;
    #pragma unroll 4
    for (int k = 0; k < Cg; ++k) {
        f4v tv = *(const f4v*)(tp + (size_t)k * HW);
        f4v sv = *(const f4v*)(sp + (size_t)k * HW);
        f4v nv = __builtin_nontemporal_load((const f4v*)(np + (size_t)k * HW));
        aT0 += tv.x*tv.x; aT1 += tv.y*tv.y; aT2 += tv.z*tv.z; aT3 += tv.w*tv.w;
        aS0 += sv.x*sv.x; aS1 += sv.y*sv.y; aS2 += sv.z*sv.z; aS3 += sv.w*sv.w;
        aN  += nv.x*nv.x + nv.y*nv.y + nv.z*nv.z + nv.w*nv.w;
    }

    // cross-wave combine via LDS overlay on cnt_sh (zeroed later)
    float* ovT = (float*)cnt_sh;       // [4][256]
    float* ovS = ovT + 1024;           // [4][256]
    float* ovN = ovT + 2048;           // [4]
    ((f4v*)(ovT + w * 256))[l] = (f4v){aT0, aT1, aT2, aT3};
    ((f4v*)(ovS + w * 256))[l] = (f4v){aS0, aS1, aS2, aS3};
    #pragma unroll
    for (int o = 32; o > 0; o >>= 1) aN += __shfl_down(aN, o, 64);
    if (l == 0) ovN[w] = aN;
    __syncthreads();

    float nT = ovT[tid] + ovT[256 + tid] + ovT[512 + tid] + ovT[768 + tid];
    float nS = ovS[tid] + ovS[256 + tid] + ovS[512 + tid] + ovS[768 + tid];
    inv_sh[tid]       = 1.0f / fmaxf(sqrtf(nT), 1e-12f);
    inv_sh[256 + tid] = 1.0f / fmaxf(sqrtf(nS), 1e-12f);
    if (tid == 0)
        atomicAdd(&ws_f[ACC_OFF + LAYER], ovN[0] + ovN[1] + ovN[2] + ovN[3]);
    __syncthreads();

    // ---- zero histogram ----
    for (int i = tid; i < NBINS / 4; i += 256)
        ((uint4*)cnt_sh)[i] = make_uint4(0u, 0u, 0u, 0u);
    __syncthreads();

    // ---- pass 2: d = (t*invT - s*invS)^2, count-only histogram ----
    f4v iT = ((const f4v*)inv_sh)[l];
    f4v iS = ((const f4v*)(inv_sh + 256))[l];
    #pragma unroll 4
    for (int k = 0; k < Cg; ++k) {
        f4v tv = __builtin_nontemporal_load((const f4v*)(tp + (size_t)k * HW));
        f4v sv = __builtin_nontemporal_load((const f4v*)(sp + (size_t)k * HW));
        float a0 = tv.x*iT.x - sv.x*iS.x;
        float a1 = tv.y*iT.y - sv.y*iS.y;
        float a2 = tv.z*iT.z - sv.z*iS.z;
        float a3 = tv.w*iT.w - sv.w*iS.w;
        float d0 = a0*a0, d1 = a1*a1, d2 = a2*a2, d3 = a3*a3;
        atomicAdd(&cnt_sh[__float_as_uint(d0) >> 18], 1u);
        atomicAdd(&cnt_sh[__float_as_uint(d1) >> 18], 1u);
        atomicAdd(&cnt_sh[__float_as_uint(d2) >> 18], 1u);
        atomicAdd(&cnt_sh[__float_as_uint(d3) >> 18], 1u);
    }
    __syncthreads();

    // ---- flush nonzero bins to global per-layer histogram ----
    unsigned int* gc = ws_u + LAYER * NBINS;
    for (int i = tid; i < NBINS; i += 256) {
        unsigned c = cnt_sh[i];
        if (c) atomicAdd(&gc[i], c);
    }
}

// Grid: 64 blocks (layer2, heaviest, first) + 256 (layer1) + 1024 (layer0) = 1344.
__global__ __launch_bounds__(256, 4) void stfpm_hist(
    const float* __restrict__ t0, const float* __restrict__ s0, const float* __restrict__ n0,
    const float* __restrict__ t1, const float* __restrict__ s1, const float* __restrict__ n1,
    const float* __restrict__ t2, const float* __restrict__ s2, const float* __restrict__ n2,
    unsigned int* __restrict__ ws_u, float* __restrict__ ws_f)
{
    __shared__ __align__(16) unsigned int cnt_sh[NBINS];  // 17.4 KB
    __shared__ __align__(16) float inv_sh[512];           // invT[256], invS[256]
    const int bid = blockIdx.x;
    if (bid < 64)
        hist_layer<256, 10, 2>(t2, s2, n2, bid,       ws_u, ws_f, cnt_sh, inv_sh);
    else if (bid < 320)
        hist_layer<128, 12, 1>(t1, s1, n1, bid - 64,  ws_u, ws_f, cnt_sh, inv_sh);
    else
        hist_layer<64,  14, 0>(t0, s0, n0, bid - 320, ws_u, ws_f, cnt_sh, inv_sh);
}

__device__ __forceinline__ float bin_mid(int b) {
    float lo = __uint_as_float((unsigned)b << 18);
    float hi = __uint_as_float((unsigned)(b + 1) << 18);
    return 0.5f * (lo + hi);
}

// Single block: per layer, scan counts from the top; full bins above the
// boundary contribute cnt * bin-midpoint; boundary bin uses the uniform-
// within-bin model for its top-j elements. Adds mean(n^2); writes the scalar.
__global__ __launch_bounds__(256) void stfpm_finalize(
    const unsigned int* __restrict__ ws_u, const float* __restrict__ ws_f,
    float* __restrict__ out)
{
    __shared__ unsigned int cchunk[256];
    __shared__ float        schunk[256];
    const int tid = threadIdx.x;

    const int   targets[3] = {16778, 8389, 4195};  // cnt = N-1-floor(0.999(N-1))
    const float Ns[3]      = {16777216.f, 8388608.f, 4194304.f};
    const int   CHUNK = NBINS / 256;  // 17

    float total = 0.f;  // thread 0 only
    for (int layer = 0; layer < 3; ++layer) {
        const unsigned int* gc = ws_u + layer * NBINS;
        unsigned int c = 0; float sv = 0.f;
        const int b0 = tid * CHUNK;
        for (int i = 0; i < CHUNK; ++i) {
            unsigned cc = gc[b0 + i];
            c += cc;
            if (cc) sv += (float)cc * bin_mid(b0 + i);
        }
        __syncthreads();
        cchunk[tid] = c; schunk[tid] = sv;
        __syncthreads();
        if (tid == 0) {
            const int target = targets[layer];
            long long cum = 0; float sAbove = 0.f;
            int ch = 255;
            while (ch >= 0 && cum + (long long)cchunk[ch] < target) {
                cum += cchunk[ch]; sAbove += schunk[ch]; --ch;
            }
            int bin = ch * CHUNK + CHUNK - 1;
            while (bin >= ch * CHUNK && cum + (long long)gc[bin] < target) {
                unsigned cc = gc[bin];
                cum += cc; sAbove += (float)cc * bin_mid(bin); --bin;
            }
            unsigned cb = gc[bin];          // boundary bin count (>=1)
            int j = target - (int)cum;      // elements taken from boundary bin
            float lo = __uint_as_float((unsigned)bin << 18);
            float hi = __uint_as_float((unsigned)(bin + 1) << 18);
            float wd = hi - lo;
            float f  = (float)j / (float)cb;
            float topmean = hi - f * wd * 0.5f;  // mean of top-j under uniform model
            topmean = fminf(fmaxf(topmean, lo), hi);
            float hard   = (sAbove + topmean * (float)j) / (float)target;
            float n2mean = ws_f[ACC_OFF + layer] / Ns[layer];
            total += hard + n2mean;
        }
        __syncthreads();
    }
    if (tid == 0) out[0] = total;
}

extern "C" void kernel_launch(void* const* d_in, const int* in_sizes, int n_in,
                              void* d_out, int out_size, void* d_ws, size_t ws_size,
                              hipStream_t stream)
{
    const float* t0 = (const float*)d_in[0];
    const float* s0 = (const float*)d_in[1];
    const float* n0 = (const float*)d_in[2];
    const float* t1 = (const float*)d_in[3];
    const float* s1 = (const float*)d_in[4];
    const float* n1 = (const float*)d_in[5];
    const float* t2 = (const float*)d_in[6];
    const float* s2 = (const float*)d_in[7];
    const float* n2 = (const float*)d_in[8];

    // zero per-layer histograms + accumulators (ws is NOT re-poisoned between replays)
    hipMemsetAsync(d_ws, 0, (size_t)(ACC_OFF + 8) * 4, stream);

    stfpm_hist<<<1344, 256, 0, stream>>>(t0, s0, n0, t1, s1, n1, t2, s2, n2,
                                         (unsigned int*)d_ws, (float*)d_ws);
    stfpm_finalize<<<1, 256, 0, stream>>>((const unsigned int*)d_ws,
                                          (const float*)d_ws, (float*)d_out);
}

// Round 4
// 84.417 us; speedup vs baseline: 4.7947x; 1.4077x over previous
//
#include <hip/hip_runtime.h>

#define NBINS 4352                 // bin = float_bits(d)>>18 ; d<=~4 -> bin<=4128
#define ACC_OFF (3 * NBINS)        // word offset of per-layer n^2 accumulators in ws

typedef float    f4v __attribute__((ext_vector_type(4)));
typedef _Float16 h4v __attribute__((ext_vector_type(4)));

// Uniform-cost fused body: every block processes 16K elements (P positions x C
// channels, P*C = 16384) of one batch image. Every thread owns exactly 16
// channels x 4 consecutive positions (one float4 per channel). Single pass:
// t,s retained in registers as f16 while f32 norms are reduced, then d is
// histogrammed from registers (no global re-read).
template<int C, int HWSHIFT, int PSHIFT, int LAYER>
__device__ __forceinline__ void hist_layer(
    const float* __restrict__ t, const float* __restrict__ s, const float* __restrict__ n,
    int lb, unsigned int* __restrict__ ws_u, float* __restrict__ ws_f,
    unsigned int* cnt_sh, float* inv_sh)
{
    const int HW  = 1 << HWSHIFT;
    const int P   = 1 << PSHIFT;        // positions per block: 256/128/64
    const int NPQ = P >> 2;             // position-quads per wave: 64/32/16
    const int G   = 1024 / P;           // norm partials per position: 4/8/16
    const int tid = threadIdx.x;
    const int w   = tid >> 6;
    const int l   = tid & 63;
    const int pq  = l & (NPQ - 1);      // which position-quad
    const int cs  = l >> (PSHIFT - 2);  // channel sub-group within wave

    const int p0 = lb << PSHIFT;        // first flat position (never straddles b)
    const int b  = p0 >> HWSHIFT;
    const int q  = p0 & (HW - 1);
    const int c0 = w * (C / 4) + cs * 16;
    const size_t base = ((size_t)(b * C + c0) << HWSHIFT) + q + 4 * pq;

    const float* tp = t + base;
    const float* sp = s + base;
    const float* np = n + base;

    // ---- pass 1: batched loads (12 float4 in flight), f32 norm accum, f16 retain ----
    h4v th[16], sh[16];
    f4v accT = {0.f,0.f,0.f,0.f}, accS = {0.f,0.f,0.f,0.f};
    float aN = 0.f;

    #pragma unroll
    for (int k0 = 0; k0 < 16; k0 += 4) {
        f4v tt[4], ss[4], nn[4];
        #pragma unroll
        for (int u = 0; u < 4; ++u) {
            const size_t o = (size_t)(k0 + u) << HWSHIFT;
            tt[u] = __builtin_nontemporal_load((const f4v*)(tp + o));
            ss[u] = __builtin_nontemporal_load((const f4v*)(sp + o));
            nn[u] = __builtin_nontemporal_load((const f4v*)(np + o));
        }
        #pragma unroll
        for (int u = 0; u < 4; ++u) {
            accT += tt[u] * tt[u];
            accS += ss[u] * ss[u];
            aN += nn[u].x*nn[u].x + nn[u].y*nn[u].y + nn[u].z*nn[u].z + nn[u].w*nn[u].w;
            th[k0+u] = (h4v){(_Float16)tt[u].x, (_Float16)tt[u].y,
                             (_Float16)tt[u].z, (_Float16)tt[u].w};
            sh[k0+u] = (h4v){(_Float16)ss[u].x, (_Float16)ss[u].y,
                             (_Float16)ss[u].z, (_Float16)ss[u].w};
        }
    }

    // cross-wave/lane-group norm combine via LDS overlay on cnt_sh
    float* ovT = (float*)cnt_sh;        // [G][P] = 1024 floats
    float* ovS = ovT + 1024;            // 1024 floats
    float* ovN = ovT + 2048;            // 4 floats
    const int g = (w * (64 / NPQ)) + cs;        // partial group id, 0..G-1
    ((f4v*)ovT)[g * NPQ + pq] = accT;           // linearizes to ovT[g*P + pos]
    ((f4v*)ovS)[g * NPQ + pq] = accS;
    #pragma unroll
    for (int o = 32; o > 0; o >>= 1) aN += __shfl_down(aN, o, 64);
    if (l == 0) ovN[w] = aN;
    __syncthreads();

    if (tid < P) {
        float nT = 0.f, nS = 0.f;
        #pragma unroll
        for (int gg = 0; gg < G; ++gg) { nT += ovT[gg * P + tid]; nS += ovS[gg * P + tid]; }
        inv_sh[tid]     = 1.0f / fmaxf(sqrtf(nT), 1e-12f);
        inv_sh[P + tid] = 1.0f / fmaxf(sqrtf(nS), 1e-12f);
    }
    if (tid == 0)
        atomicAdd(&ws_f[ACC_OFF + LAYER], ovN[0] + ovN[1] + ovN[2] + ovN[3]);
    __syncthreads();

    // ---- zero histogram ----
    for (int i = tid; i < NBINS / 4; i += 256)
        ((uint4*)cnt_sh)[i] = make_uint4(0u, 0u, 0u, 0u);
    __syncthreads();

    // ---- pass 2 (registers only): d = (t*invT - s*invS)^2, count histogram ----
    f4v iT = ((const f4v*)inv_sh)[pq];
    f4v iS = ((const f4v*)(inv_sh + P))[pq];
    #pragma unroll
    for (int k = 0; k < 16; ++k) {
        f4v tv = {(float)th[k].x, (float)th[k].y, (float)th[k].z, (float)th[k].w};
        f4v sv = {(float)sh[k].x, (float)sh[k].y, (float)sh[k].z, (float)sh[k].w};
        f4v a  = tv * iT - sv * iS;
        f4v d  = a * a;
        unsigned b0 = min(__float_as_uint(d.x) >> 18, (unsigned)(NBINS - 1));
        unsigned b1 = min(__float_as_uint(d.y) >> 18, (unsigned)(NBINS - 1));
        unsigned b2 = min(__float_as_uint(d.z) >> 18, (unsigned)(NBINS - 1));
        unsigned b3 = min(__float_as_uint(d.w) >> 18, (unsigned)(NBINS - 1));
        atomicAdd(&cnt_sh[b0], 1u);
        atomicAdd(&cnt_sh[b1], 1u);
        atomicAdd(&cnt_sh[b2], 1u);
        atomicAdd(&cnt_sh[b3], 1u);
    }
    __syncthreads();

    // ---- flush nonzero bins to global per-layer histogram ----
    unsigned int* gc = ws_u + LAYER * NBINS;
    for (int i = tid; i < NBINS; i += 256) {
        unsigned c = cnt_sh[i];
        if (c) atomicAdd(&gc[i], c);
    }
}

// Grid: 256 (layer2) + 512 (layer1) + 1024 (layer0) = 1792 = 7 * 256 uniform blocks.
__global__ __launch_bounds__(256, 3) void stfpm_hist(
    const float* __restrict__ t0, const float* __restrict__ s0, const float* __restrict__ n0,
    const float* __restrict__ t1, const float* __restrict__ s1, const float* __restrict__ n1,
    const float* __restrict__ t2, const float* __restrict__ s2, const float* __restrict__ n2,
    unsigned int* __restrict__ ws_u, float* __restrict__ ws_f)
{
    __shared__ __align__(16) unsigned int cnt_sh[NBINS];  // 17.4 KB
    __shared__ __align__(16) float inv_sh[512];
    const int bid = blockIdx.x;
    if (bid < 256)
        hist_layer<256, 10, 6, 2>(t2, s2, n2, bid,       ws_u, ws_f, cnt_sh, inv_sh);
    else if (bid < 768)
        hist_layer<128, 12, 7, 1>(t1, s1, n1, bid - 256, ws_u, ws_f, cnt_sh, inv_sh);
    else
        hist_layer<64,  14, 8, 0>(t0, s0, n0, bid - 768, ws_u, ws_f, cnt_sh, inv_sh);
}

__device__ __forceinline__ float bin_mid(int b) {
    float lo = __uint_as_float((unsigned)b << 18);
    float hi = __uint_as_float((unsigned)(b + 1) << 18);
    return 0.5f * (lo + hi);
}

// Single block: per layer, scan counts from the top; full bins above the
// boundary contribute cnt * bin-midpoint; boundary bin uses the uniform-
// within-bin model for its top-j elements. Adds mean(n^2); writes the scalar.
__global__ __launch_bounds__(256) void stfpm_finalize(
    const unsigned int* __restrict__ ws_u, const float* __restrict__ ws_f,
    float* __restrict__ out)
{
    __shared__ unsigned int cchunk[256];
    __shared__ float        schunk[256];
    const int tid = threadIdx.x;

    const int   targets[3] = {16778, 8389, 4195};  // cnt = N-1-floor(0.999(N-1))
    const float Ns[3]      = {16777216.f, 8388608.f, 4194304.f};
    const int   CHUNK = NBINS / 256;  // 17

    float total = 0.f;  // thread 0 only
    for (int layer = 0; layer < 3; ++layer) {
        const unsigned int* gc = ws_u + layer * NBINS;
        unsigned int c = 0; float sv = 0.f;
        const int b0 = tid * CHUNK;
        for (int i = 0; i < CHUNK; ++i) {
            unsigned cc = gc[b0 + i];
            c += cc;
            if (cc) sv += (float)cc * bin_mid(b0 + i);
        }
        __syncthreads();
        cchunk[tid] = c; schunk[tid] = sv;
        __syncthreads();
        if (tid == 0) {
            const int target = targets[layer];
            long long cum = 0; float sAbove = 0.f;
            int ch = 255;
            while (ch >= 0 && cum + (long long)cchunk[ch] < target) {
                cum += cchunk[ch]; sAbove += schunk[ch]; --ch;
            }
            int bin = ch * CHUNK + CHUNK - 1;
            while (bin >= ch * CHUNK && cum + (long long)gc[bin] < target) {
                unsigned cc = gc[bin];
                cum += cc; sAbove += (float)cc * bin_mid(bin); --bin;
            }
            unsigned cb = gc[bin];          // boundary bin count (>=1)
            int j = target - (int)cum;      // elements taken from boundary bin
            float lo = __uint_as_float((unsigned)bin << 18);
            float hi = __uint_as_float((unsigned)(bin + 1) << 18);
            float wd = hi - lo;
            float f  = (float)j / (float)cb;
            float topmean = hi - f * wd * 0.5f;  // mean of top-j under uniform model
            topmean = fminf(fmaxf(topmean, lo), hi);
            float hard   = (sAbove + topmean * (float)j) / (float)target;
            float n2mean = ws_f[ACC_OFF + layer] / Ns[layer];
            total += hard + n2mean;
        }
        __syncthreads();
    }
    if (tid == 0) out[0] = total;
}

extern "C" void kernel_launch(void* const* d_in, const int* in_sizes, int n_in,
                              void* d_out, int out_size, void* d_ws, size_t ws_size,
                              hipStream_t stream)
{
    const float* t0 = (const float*)d_in[0];
    const float* s0 = (const float*)d_in[1];
    const float* n0 = (const float*)d_in[2];
    const float* t1 = (const float*)d_in[3];
    const float* s1 = (const float*)d_in[4];
    const float* n1 = (const float*)d_in[5];
    const float* t2 = (const float*)d_in[6];
    const float* s2 = (const float*)d_in[7];
    const float* n2 = (const float*)d_in[8];

    // zero per-layer histograms + accumulators (ws is NOT re-poisoned between replays)
    hipMemsetAsync(d_ws, 0, (size_t)(ACC_OFF + 8) * 4, stream);

    stfpm_hist<<<1792, 256, 0, stream>>>(t0, s0, n0, t1, s1, n1, t2, s2, n2,
                                         (unsigned int*)d_ws, (float*)d_ws);
    stfpm_finalize<<<1, 256, 0, stream>>>((const unsigned int*)d_ws,
                                          (const float*)d_ws, (float*)d_out);
}